// Round 19
// baseline (176.420 us; speedup 1.0000x reference)
//
#include <hip/hip_runtime.h>
#include <stdint.h>

// E=512, H=8, D=64, B=4, Nq=Nk=2048
// bf16 MFMA pipeline: prep (cvt only) -> QKV proj GEMM (64x128 tiles, z-batched,
// Q pre-scaled, V stored token-permuted; z==3 packs the geometry mask so its
// 67 MB read overlaps the GEMM) -> flash attn (8-wave, 16 q/wave, KVBLK=128,
// LDS K/V dbuf, swapped QK^T 16x16, in-register softmax AND P, mask+bias C-init,
// deferred max merge, XCD pinning, b128 V-frags) -> out proj GEMM (64x128 tiles)

typedef __attribute__((ext_vector_type(8))) short bf16x8;  // 8 bf16 in 4 VGPRs
typedef __attribute__((ext_vector_type(4))) float f32x4;

#define SCLQ 0.18033688011112042f  // 0.125 * log2(e): logits emerge in log2 domain

static __device__ __forceinline__ unsigned short f2bf(float f) {
    union { float f; unsigned u; } x; x.f = f;
    unsigned r = x.u + 0x7fffu + ((x.u >> 16) & 1u);  // RTN-even
    return (unsigned short)(r >> 16);
}

static __device__ __forceinline__ f32x4 mfma16(bf16x8 a, bf16x8 b, f32x4 c) {
    return __builtin_amdgcn_mfma_f32_16x16x32_bf16(a, b, c, 0, 0, 0);
}

#define GLOAD_LDS16(g, l)                                                            \
    __builtin_amdgcn_global_load_lds((const __attribute__((address_space(1))) void*)(g), \
                                     (__attribute__((address_space(3))) void*)(l), 16, 0, 0)

// ---------------- prep: cvt_x (12288 blocks) + cvt_wt (512) ----------------
__global__ __launch_bounds__(256) void prep_kernel(
    const float* __restrict__ q, const float* __restrict__ k, const float* __restrict__ v,
    const float* __restrict__ Wq, const float* __restrict__ Wk,
    const float* __restrict__ Wv, const float* __restrict__ Wo,
    short* __restrict__ Xq, short* __restrict__ Xk, short* __restrict__ Xv,
    short* __restrict__ WqT, short* __restrict__ WkT,
    short* __restrict__ WvT, short* __restrict__ WoT)
{
    int bx = blockIdx.x;
    if (bx < 12288) {  // fp32 -> bf16, 4 elems/thread (float4 -> short4)
        int z = bx >> 12;
        const float* src = (z == 0) ? q : (z == 1) ? k : v;
        short* dst = (z == 0) ? Xq : (z == 1) ? Xk : Xv;
        size_t i = (size_t)(bx & 4095) * 256 + threadIdx.x;
        float4 vv = ((const float4*)src)[i];
        short4 o;
        o.x = (short)f2bf(vv.x); o.y = (short)f2bf(vv.y);
        o.z = (short)f2bf(vv.z); o.w = (short)f2bf(vv.w);
        ((short4*)dst)[i] = o;
    } else {  // W[k][n] fp32 -> WT[n][k] bf16
        int b2 = bx - 12288;
        int z = b2 >> 7;
        const float* W = (z == 0) ? Wq : (z == 1) ? Wk : (z == 2) ? Wv : Wo;
        short* WT = (z == 0) ? WqT : (z == 1) ? WkT : (z == 2) ? WvT : WoT;
        int t = (b2 & 127) * 256 + threadIdx.x;
        int n = t & 511;
        int k0 = (t >> 9) * 8;
        union { short s[8]; int4 v4; } u;
#pragma unroll
        for (int j = 0; j < 8; ++j) u.s[j] = (short)f2bf(W[(size_t)(k0 + j) * 512 + n]);
        *(int4*)(WT + (size_t)n * 512 + k0) = u.v4;
    }
}

// ---------------- GEMM body (64x128 tile): C[8192x512] = A @ W (+bias) ----------------
// mode 0: Q -> [b,h,tok,d] bf16, pre-scaled ; 1: K -> [b,h,tok,d]
// mode 2: V -> [b,h,d,ptok] bf16 with tokens PERMUTED within 32-groups so attn's
//         sigma16 V B-frags are contiguous b128 reads: storage s holds token
//         t = 4*(s>>3) + (s&3) + 16*((s>>2)&1); inverse s = ((t>>2)&3)<<3 |
//         ((t>>4)&1)<<2 | (t&3).
// mode 3: fp32 row-major out.  256 thr / 4 waves; wave = 32x64 (2x4 frags).
static __device__ __forceinline__ void gemm_body(
    const short* __restrict__ A, const short* __restrict__ BT,
    const float* __restrict__ bias, void* __restrict__ Cout, int mode,
    char* lds, int bx, int by)
{
    const int tid = threadIdx.x;
    const int lane = tid & 63;
    const int wid = tid >> 6;
    const int l15 = lane & 15, l4 = lane >> 4;
    const int m0 = by * 64;
    const int n0 = bx * 128;
    const int wr = wid >> 1, wc = wid & 1;

    f32x4 zero = {0.f, 0.f, 0.f, 0.f};
    f32x4 acc[2][4];
#pragma unroll
    for (int i = 0; i < 2; ++i)
#pragma unroll
        for (int j = 0; j < 4; ++j) acc[i][j] = zero;

    char* Alds = lds;          // 64 x 128B = 8 KB
    char* Blds = lds + 8192;   // 128 x 128B = 16 KB

    for (int t = 0; t < 8; ++t) {
        const int k0 = t * 64;
#pragma unroll
        for (int s = 0; s < 2; ++s) {  // A: 2 shots (rows 0..63)
            int p = s * 256 + tid;
            int r = p >> 3, c = p & 7;
            GLOAD_LDS16(A + (size_t)(m0 + r) * 512 + k0 + 8 * (c ^ (r & 7)),
                        Alds + s * 4096 + wid * 1024);
        }
#pragma unroll
        for (int s = 0; s < 4; ++s) {  // B: 4 shots (rows 0..127)
            int p = s * 256 + tid;
            int r = p >> 3, c = p & 7;
            GLOAD_LDS16(BT + (size_t)(n0 + r) * 512 + k0 + 8 * (c ^ (r & 7)),
                        Blds + s * 4096 + wid * 1024);
        }
        __syncthreads();
#pragma unroll
        for (int ks = 0; ks < 2; ++ks) {
            bf16x8 af[2], bfr[4];
#pragma unroll
            for (int mb = 0; mb < 2; ++mb) {
                int row = wr * 32 + mb * 16 + l15;
                af[mb] = *(const bf16x8*)(Alds + row * 128 +
                                          ((ks * 64 + l4 * 16) ^ ((row & 7) << 4)));
            }
#pragma unroll
            for (int nb = 0; nb < 4; ++nb) {
                int row = wc * 64 + nb * 16 + l15;
                bfr[nb] = *(const bf16x8*)(Blds + row * 128 +
                                           ((ks * 64 + l4 * 16) ^ ((row & 7) << 4)));
            }
#pragma unroll
            for (int mb = 0; mb < 2; ++mb)
#pragma unroll
                for (int nb = 0; nb < 4; ++nb)
                    acc[mb][nb] = mfma16(af[mb], bfr[nb], acc[mb][nb]);
        }
        __syncthreads();
    }

#pragma unroll
    for (int nb = 0; nb < 4; ++nb) {
        int n = n0 + wc * 64 + nb * 16 + l15;
        float bv = bias[n];
#pragma unroll
        for (int mb = 0; mb < 2; ++mb) {
#pragma unroll
            for (int r = 0; r < 4; ++r) {
                int m = m0 + wr * 32 + mb * 16 + l4 * 4 + r;
                float val = acc[mb][nb][r] + bv;
                if (mode == 0) val *= SCLQ;  // fold softmax scale+log2e into Q
                if (mode == 3) {
                    ((float*)Cout)[(size_t)m * 512 + n] = val;
                } else {
                    int b = m >> 11, tok = m & 2047;
                    int h = n >> 6, d = n & 63;
                    short* o = (short*)Cout;
                    if (mode == 2) {
                        // token permutation within 32-group (sigma16 pre-image)
                        int ptok = (tok & ~31) | (tok & 3) |
                                   (((tok >> 4) & 1) << 2) | (((tok >> 2) & 3) << 3);
                        o[((size_t)(b * 8 + h) * 64 + d) * 2048 + ptok] = (short)f2bf(val);
                    } else {
                        o[((size_t)(b * 8 + h) * 2048 + tok) * 64 + d] = (short)f2bf(val);
                    }
                }
            }
        }
    }
}

// z-batched QKV projection: blockIdx.z in {0,1,2} selects {Q,K,V}; z==3 packs the
// geometry mask (R15-validated branch: 512 blocks x 16 rows = all 8192 rows), so the
// mask's 67 MB HBM read overlaps the GEMM work. grid (4,128,4).
__global__ __launch_bounds__(256) void gemm_qkv_kernel(
    const short* __restrict__ Xq, const short* __restrict__ Xk, const short* __restrict__ Xv,
    const short* __restrict__ WqT, const short* __restrict__ WkT, const short* __restrict__ WvT,
    const float* __restrict__ bq, const float* __restrict__ bk, const float* __restrict__ bv,
    short* __restrict__ Qw, short* __restrict__ Kw, short* __restrict__ VTw,
    const int* __restrict__ gm, unsigned long long* __restrict__ mp)
{
    __shared__ char lds[24576];
    int z = blockIdx.z;
    if (z == 3) {  // mask (4-byte elems, nonzero=keep) -> packed bits; ALL 8192 rows
        int bid = blockIdx.y * 4 + blockIdx.x;  // 0..511, 16 rows each
        int lane = threadIdx.x & 63;
        int wv = threadIdx.x >> 6;              // 0..3
#pragma unroll
        for (int p = 0; p < 4; ++p) {
            int row = bid * 16 + p * 4 + wv;    // 0..8191 = b*2048+q
            const int* mrow = gm + (size_t)row * 2048;
#pragma unroll 4
            for (int w = 0; w < 32; ++w) {
                unsigned long long bits = __ballot(mrow[w * 64 + lane] != 0);
                if (lane == 0) mp[(size_t)row * 32 + w] = bits;
            }
        }
        return;
    }
    const short* A = (z == 0) ? Xq : (z == 1) ? Xk : Xv;
    const short* BT = (z == 0) ? WqT : (z == 1) ? WkT : WvT;
    const float* bias = (z == 0) ? bq : (z == 1) ? bk : bv;
    void* Cout = (z == 0) ? (void*)Qw : (z == 1) ? (void*)Kw : (void*)VTw;
    gemm_body(A, BT, bias, Cout, z, lds, blockIdx.x, blockIdx.y);
}

__global__ __launch_bounds__(256) void gemm_kernel(
    const short* __restrict__ A, const short* __restrict__ BT,
    const float* __restrict__ bias, void* __restrict__ Cout, int mode)
{
    __shared__ char lds[24576];
    gemm_body(A, BT, bias, Cout, mode, lds, blockIdx.x, blockIdx.y);
}

// ---------------- masked flash attention: 8-wave, 16 q/wave, KVBLK=128 ----------------
// grid 512 = 8 XCD x 4 bh x 16 q-chunks of 128 (xcd = lid&7 pins bh to one XCD's L2).
// Per outer iteration: stage 128 tokens of K and V into 16KB-per-operand double
// buffers, run the 64-token body twice, ONE barrier. Swapped QK^T (S^T col=l15=q,
// row=l4*4+r=k); mask C-init (bit ? -mrun : -1e30); deferred max merge (T13);
// in-register P via sigma16. V is stored token-permuted (GEMM mode 2), so each
// V B-frag is ONE ds_read_b128 at granule (kb*4+l4)^swl (+H*128) — no marshal.
__global__ __launch_bounds__(512) void attn_kernel(
    const short* __restrict__ Q, const short* __restrict__ K,
    const short* __restrict__ VT, const unsigned long long* __restrict__ mp,
    short* __restrict__ AO)
{
    __shared__ char lds[65536];  // K dbuf 2x16KB @0; V dbuf 2x16KB @32768
    const int tid = threadIdx.x;
    const int lane = tid & 63;
    const int wid = tid >> 6;
    const int l15 = lane & 15, l4 = lane >> 4;
    const int lid = blockIdx.x;
    const int xcd = lid & 7, jj = lid >> 3;
    const int bhi = (xcd << 2) | (jj >> 4);
    const int b = bhi >> 3, h = bhi & 7;
    const int q0 = (jj & 15) * 128 + wid * 16;
    const short* Qp = Q + ((size_t)bhi * 2048 + q0) * 64;
    const short* Kp = K + (size_t)bhi * 2048 * 64;
    const short* Vp = VT + (size_t)bhi * 64 * 2048;

    // staging maps (pre-swizzled global source; LDS dest linear = wavebase + lane*16)
    const int krow = tid >> 3;
    const int kgo  = 8 * ((tid & 7) ^ (krow & 7));
    const int vrow0 = tid >> 4;
    const int vgo   = 8 * ((tid & 15) ^ (vrow0 & 7));
    const int vrow1 = 32 + vrow0;
    const int swl = l15 & 7;  // read-side swizzle key (row & 7)

#define STAGE(KT, BUF)                                                               \
    {                                                                                \
        const short* Kn = Kp + (size_t)(KT) * 128 * 64;                              \
        char* Kd = lds + (BUF) * 16384;                                              \
        GLOAD_LDS16(Kn + (size_t)krow * 64 + kgo, Kd + wid * 1024);                  \
        GLOAD_LDS16(Kn + (size_t)(64 + krow) * 64 + kgo, Kd + 8192 + wid * 1024);    \
        const short* Vn = Vp + (KT) * 128;                                           \
        char* Vd = lds + 32768 + (BUF) * 16384;                                      \
        GLOAD_LDS16(Vn + (size_t)vrow0 * 2048 + vgo, Vd + wid * 1024);               \
        GLOAD_LDS16(Vn + (size_t)vrow1 * 2048 + vgo, Vd + 8192 + wid * 1024);        \
    }

    // Q B-frags: qb[dc] = Q[q0+l15][dc*32+l4*8+j]
    bf16x8 qb[2];
#pragma unroll
    for (int dc = 0; dc < 2; ++dc)
        qb[dc] = *(const bf16x8*)(Qp + l15 * 64 + dc * 32 + l4 * 8);

    f32x4 o[4];  // o[dt]: q = l4*4 + r, d = dt*16 + l15
#pragma unroll
    for (int dt = 0; dt < 4; ++dt) o[dt] = f32x4{0.f, 0.f, 0.f, 0.f};
    float mrun = 0.f, lrun = 0.f;  // violation raises mrun if needed (T13)

    const unsigned long long* mr0 = mp + ((size_t)b * 2048 + q0 + l15) * 32;

    STAGE(0, 0)
    ulonglong2 mwv = *(const ulonglong2*)(mr0);   // words for tile 0 (halves 0,1)
    __syncthreads();

// one 64-token half. H = 0/1 selects LDS sub-tile; MW = mask word.
#define HALF(H, MW)                                                                  \
    {                                                                                \
        bf16x8 ka[4][2];                                                             \
        _Pragma("unroll") for (int tb = 0; tb < 4; ++tb)                             \
            _Pragma("unroll") for (int dc = 0; dc < 2; ++dc)                         \
                ka[tb][dc] = *(const bf16x8*)(Kc + (H) * 8192 +                      \
                                              (tb * 16 + l15) * 128 +                \
                                              16 * ((dc * 4 + l4) ^ swl));           \
        bf16x8 vb[4][2];                                                             \
        _Pragma("unroll") for (int dt = 0; dt < 4; ++dt)                             \
            _Pragma("unroll") for (int kb = 0; kb < 2; ++kb)                         \
                vb[dt][kb] = *(const bf16x8*)(Vc + (dt * 16 + l15) * 256 +           \
                                              (H) * 128 +                            \
                                              16 * ((kb * 4 + l4) ^ swl));           \
        const float nm = -mrun;                                                      \
        unsigned long long u64 = (MW) >> (l4 * 4);                                   \
        unsigned ulo = (unsigned)u64, uhi = (unsigned)(u64 >> 32);                   \
        f32x4 sv[4];                                                                 \
        _Pragma("unroll") for (int tb = 0; tb < 4; ++tb) {                           \
            unsigned us = (tb & 2) ? uhi : ulo;                                      \
            f32x4 i0;                                                                \
            _Pragma("unroll") for (int r = 0; r < 4; ++r)                            \
                i0[r] = (us & (1u << (((tb & 1) << 4) + r))) ? nm : -1e30f;          \
            sv[tb] = mfma16(ka[tb][1], qb[1], mfma16(ka[tb][0], qb[0], i0));         \
        }                                                                            \
        float pml;                                                                   \
        {                                                                            \
            f32x4 m0v;                                                               \
            _Pragma("unroll") for (int r = 0; r < 4; ++r)                            \
                m0v[r] = fmaxf(fmaxf(sv[0][r], sv[1][r]), fmaxf(sv[2][r], sv[3][r]));\
            pml = fmaxf(fmaxf(m0v[0], m0v[1]), fmaxf(m0v[2], m0v[3]));               \
        }                                                                            \
        if (__any(pml > 8.f)) {                                                      \
            float pm = fmaxf(pml, __shfl_xor(pml, 16, 64));                          \
            pm = fmaxf(pm, __shfl_xor(pm, 32, 64));                                  \
            float dm = fmaxf(pm, 0.f);                                               \
            float al = exp2f(-dm);                                                   \
            mrun += dm;                                                              \
            lrun *= al;                                                              \
            _Pragma("unroll") for (int r = 0; r < 4; ++r) {                          \
                float alr = __shfl(al, l4 * 4 + r, 64);                              \
                _Pragma("unroll") for (int dt = 0; dt < 4; ++dt) o[dt][r] *= alr;    \
            }                                                                        \
            _Pragma("unroll") for (int tb = 0; tb < 4; ++tb)                         \
                _Pragma("unroll") for (int r = 0; r < 4; ++r) sv[tb][r] -= dm;       \
        }                                                                            \
        _Pragma("unroll") for (int tb = 0; tb < 4; ++tb)                             \
            _Pragma("unroll") for (int r = 0; r < 4; ++r)                            \
                sv[tb][r] = exp2f(sv[tb][r]);                                        \
        {                                                                            \
            f32x4 t0 = (sv[0] + sv[1]) + (sv[2] + sv[3]);                            \
            lrun += (t0[0] + t0[1]) + (t0[2] + t0[3]);                               \
        }                                                                            \
        bf16x8 pa[2];                                                                \
        {                                                                            \
            uint4 t_;                                                                \
            asm("v_cvt_pk_bf16_f32 %0, %1, %2" : "=v"(t_.x) : "v"(sv[0][0]), "v"(sv[0][1])); \
            asm("v_cvt_pk_bf16_f32 %0, %1, %2" : "=v"(t_.y) : "v"(sv[0][2]), "v"(sv[0][3])); \
            asm("v_cvt_pk_bf16_f32 %0, %1, %2" : "=v"(t_.z) : "v"(sv[1][0]), "v"(sv[1][1])); \
            asm("v_cvt_pk_bf16_f32 %0, %1, %2" : "=v"(t_.w) : "v"(sv[1][2]), "v"(sv[1][3])); \
            pa[0] = *(bf16x8*)&t_;                                                   \
            asm("v_cvt_pk_bf16_f32 %0, %1, %2" : "=v"(t_.x) : "v"(sv[2][0]), "v"(sv[2][1])); \
            asm("v_cvt_pk_bf16_f32 %0, %1, %2" : "=v"(t_.y) : "v"(sv[2][2]), "v"(sv[2][3])); \
            asm("v_cvt_pk_bf16_f32 %0, %1, %2" : "=v"(t_.z) : "v"(sv[3][0]), "v"(sv[3][1])); \
            asm("v_cvt_pk_bf16_f32 %0, %1, %2" : "=v"(t_.w) : "v"(sv[3][2]), "v"(sv[3][3])); \
            pa[1] = *(bf16x8*)&t_;                                                   \
        }                                                                            \
        _Pragma("unroll") for (int dt = 0; dt < 4; ++dt)                             \
            o[dt] = mfma16(pa[1], vb[dt][1], mfma16(pa[0], vb[dt][0], o[dt]));       \
    }

    for (int kt = 0; kt < 16; ++kt) {
        const int cur = kt & 1;
        char* Kc = lds + cur * 16384;
        char* Vc = lds + 32768 + cur * 16384;
        if (kt < 15) STAGE(kt + 1, cur ^ 1)
        ulonglong2 mwn;
        mwn.x = 0; mwn.y = 0;
        if (kt < 15) mwn = *(const ulonglong2*)(mr0 + 2 * kt + 2);
        HALF(0, mwv.x)
        HALF(1, mwv.y)
        mwv = mwn;
        __syncthreads();  // drains next-tile staging + all LDS reads; swap buffers
    }
#undef HALF
#undef STAGE

    // epilogue: merge l4-group partial sums, normalize, store
    {
        float lt = lrun;
        lt += __shfl_xor(lt, 16, 64);
        lt += __shfl_xor(lt, 32, 64);
        float inv = 1.0f / lt;  // for q = q0 + l15
#pragma unroll
        for (int r = 0; r < 4; ++r) {
            float invr = __shfl(inv, l4 * 4 + r, 64);
            size_t base = ((size_t)b * 2048 + q0 + l4 * 4 + r) * 512 + h * 64;
#pragma unroll
            for (int dt = 0; dt < 4; ++dt)
                AO[base + dt * 16 + l15] = (short)f2bf(o[dt][r] * invr);
        }
    }
}

// ---------------- launcher ----------------
extern "C" void kernel_launch(void* const* d_in, const int* in_sizes, int n_in,
                              void* d_out, int out_size, void* d_ws, size_t ws_size,
                              hipStream_t stream) {
    const float* q  = (const float*)d_in[0];
    const float* k  = (const float*)d_in[1];
    const float* v  = (const float*)d_in[2];
    const int*   gm = (const int*)d_in[3];
    const float* Wq = (const float*)d_in[4];  const float* bq = (const float*)d_in[5];
    const float* Wk = (const float*)d_in[6];  const float* bk = (const float*)d_in[7];
    const float* Wv = (const float*)d_in[8];  const float* bv = (const float*)d_in[9];
    const float* Wo = (const float*)d_in[10]; const float* bo = (const float*)d_in[11];

    char* ws = (char*)d_ws;
    short* Xq  = (short*)(ws + 0);
    short* Xk  = (short*)(ws + 8388608);
    short* Xv  = (short*)(ws + 16777216);
    short* WqT = (short*)(ws + 25165824);
    short* WkT = (short*)(ws + 25690112);
    short* WvT = (short*)(ws + 26214400);
    short* WoT = (short*)(ws + 26738688);
    short* Qw  = (short*)(ws + 27262976);    // [b,h,tok,d] (pre-scaled)
    short* Kw  = (short*)(ws + 35651584);    // [b,h,tok,d]
    short* VTw = (short*)(ws + 44040192);    // [b,h,d,ptok] (token-permuted)
    short* AO  = (short*)(ws + 52428800);    // attn out [b,tok,h*64+d]
    unsigned long long* MP = (unsigned long long*)(ws + 60817408);

    prep_kernel<<<dim3(12800), 256, 0, stream>>>(q, k, v, Wq, Wk, Wv, Wo,
                                                 Xq, Xk, Xv, WqT, WkT, WvT, WoT);

    gemm_qkv_kernel<<<dim3(4, 128, 4), 256, 0, stream>>>(Xq, Xk, Xv, WqT, WkT, WvT,
                                                         bq, bk, bv, Qw, Kw, VTw,
                                                         gm, MP);

    attn_kernel<<<dim3(512), 512, 0, stream>>>(Qw, Kw, VTw, MP, AO);

    gemm_kernel<<<dim3(4, 128), 256, 0, stream>>>(AO, WoT, bo, (void*)d_out, 3);
}

// Round 20
// 153.240 us; speedup vs baseline: 1.1513x; 1.1513x over previous
//
#include <hip/hip_runtime.h>
#include <stdint.h>

// E=512, H=8, D=64, B=4, Nq=Nk=2048
// FINAL (= R16/R18, best measured 153.6 us): prep (cvt+mask, one launch) ->
// QKV proj GEMM (64x128 tiles, z-batched, Q pre-scaled, V stored token-permuted)
// -> flash attn (8-wave, 16 q/wave, KVBLK=128, LDS K/V dbuf, swapped QK^T 16x16,
// in-register softmax AND P, mask+bias C-init, deferred max merge, XCD pinning,
// b128 V-frags) -> out proj GEMM (64x128 tiles).
// R19's mask-overlap graft regressed (mask blocks tail the GEMM launch) — reverted.

typedef __attribute__((ext_vector_type(8))) short bf16x8;  // 8 bf16 in 4 VGPRs
typedef __attribute__((ext_vector_type(4))) float f32x4;

#define SCLQ 0.18033688011112042f  // 0.125 * log2(e): logits emerge in log2 domain

static __device__ __forceinline__ unsigned short f2bf(float f) {
    union { float f; unsigned u; } x; x.f = f;
    unsigned r = x.u + 0x7fffu + ((x.u >> 16) & 1u);  // RTN-even
    return (unsigned short)(r >> 16);
}

static __device__ __forceinline__ f32x4 mfma16(bf16x8 a, bf16x8 b, f32x4 c) {
    return __builtin_amdgcn_mfma_f32_16x16x32_bf16(a, b, c, 0, 0, 0);
}

#define GLOAD_LDS16(g, l)                                                            \
    __builtin_amdgcn_global_load_lds((const __attribute__((address_space(1))) void*)(g), \
                                     (__attribute__((address_space(3))) void*)(l), 16, 0, 0)

// ---------------- prep: cvt_x (12288 blocks) + cvt_wt (512) + pack_mask (2048) ----------------
__global__ __launch_bounds__(256) void prep_kernel(
    const float* __restrict__ q, const float* __restrict__ k, const float* __restrict__ v,
    const int* __restrict__ gm,
    const float* __restrict__ Wq, const float* __restrict__ Wk,
    const float* __restrict__ Wv, const float* __restrict__ Wo,
    short* __restrict__ Xq, short* __restrict__ Xk, short* __restrict__ Xv,
    short* __restrict__ WqT, short* __restrict__ WkT,
    short* __restrict__ WvT, short* __restrict__ WoT,
    unsigned long long* __restrict__ mp)
{
    int bx = blockIdx.x;
    if (bx < 12288) {  // fp32 -> bf16, 4 elems/thread (float4 -> short4)
        int z = bx >> 12;
        const float* src = (z == 0) ? q : (z == 1) ? k : v;
        short* dst = (z == 0) ? Xq : (z == 1) ? Xk : Xv;
        size_t i = (size_t)(bx & 4095) * 256 + threadIdx.x;
        float4 vv = ((const float4*)src)[i];
        short4 o;
        o.x = (short)f2bf(vv.x); o.y = (short)f2bf(vv.y);
        o.z = (short)f2bf(vv.z); o.w = (short)f2bf(vv.w);
        ((short4*)dst)[i] = o;
    } else if (bx < 12800) {  // W[k][n] fp32 -> WT[n][k] bf16
        int b2 = bx - 12288;
        int z = b2 >> 7;
        const float* W = (z == 0) ? Wq : (z == 1) ? Wk : (z == 2) ? Wv : Wo;
        short* WT = (z == 0) ? WqT : (z == 1) ? WkT : (z == 2) ? WvT : WoT;
        int t = (b2 & 127) * 256 + threadIdx.x;
        int n = t & 511;
        int k0 = (t >> 9) * 8;
        union { short s[8]; int4 v4; } u;
#pragma unroll
        for (int j = 0; j < 8; ++j) u.s[j] = (short)f2bf(W[(size_t)(k0 + j) * 512 + n]);
        *(int4*)(WT + (size_t)n * 512 + k0) = u.v4;
    } else {  // mask (4-byte elems, nonzero=keep) -> packed bits
        int b3 = bx - 12800;
        int lane = threadIdx.x & 63;
        int row = b3 * 4 + (threadIdx.x >> 6);  // b*2048+q
        const int* mrow = gm + (size_t)row * 2048;
#pragma unroll 4
        for (int w = 0; w < 32; ++w) {
            unsigned long long bits = __ballot(mrow[w * 64 + lane] != 0);
            if (lane == 0) mp[(size_t)row * 32 + w] = bits;
        }
    }
}

// ---------------- GEMM body (64x128 tile): C[8192x512] = A @ W (+bias) ----------------
// mode 0: Q -> [b,h,tok,d] bf16, pre-scaled ; 1: K -> [b,h,tok,d]
// mode 2: V -> [b,h,d,ptok] bf16 with tokens PERMUTED within 32-groups so attn's
//         sigma16 V B-frags are contiguous b128 reads: storage s holds token
//         t = 4*(s>>3) + (s&3) + 16*((s>>2)&1); inverse s = ((t>>2)&3)<<3 |
//         ((t>>4)&1)<<2 | (t&3).
// mode 3: fp32 row-major out.  256 thr / 4 waves; wave = 32x64 (2x4 frags).
static __device__ __forceinline__ void gemm_body(
    const short* __restrict__ A, const short* __restrict__ BT,
    const float* __restrict__ bias, void* __restrict__ Cout, int mode,
    char* lds, int bx, int by)
{
    const int tid = threadIdx.x;
    const int lane = tid & 63;
    const int wid = tid >> 6;
    const int l15 = lane & 15, l4 = lane >> 4;
    const int m0 = by * 64;
    const int n0 = bx * 128;
    const int wr = wid >> 1, wc = wid & 1;

    f32x4 zero = {0.f, 0.f, 0.f, 0.f};
    f32x4 acc[2][4];
#pragma unroll
    for (int i = 0; i < 2; ++i)
#pragma unroll
        for (int j = 0; j < 4; ++j) acc[i][j] = zero;

    char* Alds = lds;          // 64 x 128B = 8 KB
    char* Blds = lds + 8192;   // 128 x 128B = 16 KB

    for (int t = 0; t < 8; ++t) {
        const int k0 = t * 64;
#pragma unroll
        for (int s = 0; s < 2; ++s) {  // A: 2 shots (rows 0..63)
            int p = s * 256 + tid;
            int r = p >> 3, c = p & 7;
            GLOAD_LDS16(A + (size_t)(m0 + r) * 512 + k0 + 8 * (c ^ (r & 7)),
                        Alds + s * 4096 + wid * 1024);
        }
#pragma unroll
        for (int s = 0; s < 4; ++s) {  // B: 4 shots (rows 0..127)
            int p = s * 256 + tid;
            int r = p >> 3, c = p & 7;
            GLOAD_LDS16(BT + (size_t)(n0 + r) * 512 + k0 + 8 * (c ^ (r & 7)),
                        Blds + s * 4096 + wid * 1024);
        }
        __syncthreads();
#pragma unroll
        for (int ks = 0; ks < 2; ++ks) {
            bf16x8 af[2], bfr[4];
#pragma unroll
            for (int mb = 0; mb < 2; ++mb) {
                int row = wr * 32 + mb * 16 + l15;
                af[mb] = *(const bf16x8*)(Alds + row * 128 +
                                          ((ks * 64 + l4 * 16) ^ ((row & 7) << 4)));
            }
#pragma unroll
            for (int nb = 0; nb < 4; ++nb) {
                int row = wc * 64 + nb * 16 + l15;
                bfr[nb] = *(const bf16x8*)(Blds + row * 128 +
                                           ((ks * 64 + l4 * 16) ^ ((row & 7) << 4)));
            }
#pragma unroll
            for (int mb = 0; mb < 2; ++mb)
#pragma unroll
                for (int nb = 0; nb < 4; ++nb)
                    acc[mb][nb] = mfma16(af[mb], bfr[nb], acc[mb][nb]);
        }
        __syncthreads();
    }

#pragma unroll
    for (int nb = 0; nb < 4; ++nb) {
        int n = n0 + wc * 64 + nb * 16 + l15;
        float bv = bias[n];
#pragma unroll
        for (int mb = 0; mb < 2; ++mb) {
#pragma unroll
            for (int r = 0; r < 4; ++r) {
                int m = m0 + wr * 32 + mb * 16 + l4 * 4 + r;
                float val = acc[mb][nb][r] + bv;
                if (mode == 0) val *= SCLQ;  // fold softmax scale+log2e into Q
                if (mode == 3) {
                    ((float*)Cout)[(size_t)m * 512 + n] = val;
                } else {
                    int b = m >> 11, tok = m & 2047;
                    int h = n >> 6, d = n & 63;
                    short* o = (short*)Cout;
                    if (mode == 2) {
                        // token permutation within 32-group (sigma16 pre-image)
                        int ptok = (tok & ~31) | (tok & 3) |
                                   (((tok >> 4) & 1) << 2) | (((tok >> 2) & 3) << 3);
                        o[((size_t)(b * 8 + h) * 64 + d) * 2048 + ptok] = (short)f2bf(val);
                    } else {
                        o[((size_t)(b * 8 + h) * 2048 + tok) * 64 + d] = (short)f2bf(val);
                    }
                }
            }
        }
    }
}

// z-batched QKV projection: blockIdx.z selects {Q,K,V}; grid (4,128,3)
__global__ __launch_bounds__(256) void gemm_qkv_kernel(
    const short* __restrict__ Xq, const short* __restrict__ Xk, const short* __restrict__ Xv,
    const short* __restrict__ WqT, const short* __restrict__ WkT, const short* __restrict__ WvT,
    const float* __restrict__ bq, const float* __restrict__ bk, const float* __restrict__ bv,
    short* __restrict__ Qw, short* __restrict__ Kw, short* __restrict__ VTw)
{
    __shared__ char lds[24576];
    int z = blockIdx.z;
    const short* A = (z == 0) ? Xq : (z == 1) ? Xk : Xv;
    const short* BT = (z == 0) ? WqT : (z == 1) ? WkT : WvT;
    const float* bias = (z == 0) ? bq : (z == 1) ? bk : bv;
    void* Cout = (z == 0) ? (void*)Qw : (z == 1) ? (void*)Kw : (void*)VTw;
    gemm_body(A, BT, bias, Cout, z, lds, blockIdx.x, blockIdx.y);
}

__global__ __launch_bounds__(256) void gemm_kernel(
    const short* __restrict__ A, const short* __restrict__ BT,
    const float* __restrict__ bias, void* __restrict__ Cout, int mode)
{
    __shared__ char lds[24576];
    gemm_body(A, BT, bias, Cout, mode, lds, blockIdx.x, blockIdx.y);
}

// ---------------- masked flash attention: 8-wave, 16 q/wave, KVBLK=128 ----------------
// grid 512 = 8 XCD x 4 bh x 16 q-chunks of 128 (xcd = lid&7 pins bh to one XCD's L2).
// Per outer iteration: stage 128 tokens of K and V into 16KB-per-operand double
// buffers, run the 64-token body twice, ONE barrier. Swapped QK^T (S^T col=l15=q,
// row=l4*4+r=k); mask C-init (bit ? -mrun : -1e30); deferred max merge (T13);
// in-register P via sigma16. V is stored token-permuted (GEMM mode 2), so each
// V B-frag is ONE ds_read_b128 at granule (kb*4+l4)^swl (+H*128) — no marshal.
__global__ __launch_bounds__(512) void attn_kernel(
    const short* __restrict__ Q, const short* __restrict__ K,
    const short* __restrict__ VT, const unsigned long long* __restrict__ mp,
    short* __restrict__ AO)
{
    __shared__ char lds[65536];  // K dbuf 2x16KB @0; V dbuf 2x16KB @32768
    const int tid = threadIdx.x;
    const int lane = tid & 63;
    const int wid = tid >> 6;
    const int l15 = lane & 15, l4 = lane >> 4;
    const int lid = blockIdx.x;
    const int xcd = lid & 7, jj = lid >> 3;
    const int bhi = (xcd << 2) | (jj >> 4);
    const int b = bhi >> 3, h = bhi & 7;
    const int q0 = (jj & 15) * 128 + wid * 16;
    const short* Qp = Q + ((size_t)bhi * 2048 + q0) * 64;
    const short* Kp = K + (size_t)bhi * 2048 * 64;
    const short* Vp = VT + (size_t)bhi * 64 * 2048;

    // staging maps (pre-swizzled global source; LDS dest linear = wavebase + lane*16)
    const int krow = tid >> 3;
    const int kgo  = 8 * ((tid & 7) ^ (krow & 7));
    const int vrow0 = tid >> 4;
    const int vgo   = 8 * ((tid & 15) ^ (vrow0 & 7));
    const int vrow1 = 32 + vrow0;
    const int swl = l15 & 7;  // read-side swizzle key (row & 7)

#define STAGE(KT, BUF)                                                               \
    {                                                                                \
        const short* Kn = Kp + (size_t)(KT) * 128 * 64;                              \
        char* Kd = lds + (BUF) * 16384;                                              \
        GLOAD_LDS16(Kn + (size_t)krow * 64 + kgo, Kd + wid * 1024);                  \
        GLOAD_LDS16(Kn + (size_t)(64 + krow) * 64 + kgo, Kd + 8192 + wid * 1024);    \
        const short* Vn = Vp + (KT) * 128;                                           \
        char* Vd = lds + 32768 + (BUF) * 16384;                                      \
        GLOAD_LDS16(Vn + (size_t)vrow0 * 2048 + vgo, Vd + wid * 1024);               \
        GLOAD_LDS16(Vn + (size_t)vrow1 * 2048 + vgo, Vd + 8192 + wid * 1024);        \
    }

    // Q B-frags: qb[dc] = Q[q0+l15][dc*32+l4*8+j]
    bf16x8 qb[2];
#pragma unroll
    for (int dc = 0; dc < 2; ++dc)
        qb[dc] = *(const bf16x8*)(Qp + l15 * 64 + dc * 32 + l4 * 8);

    f32x4 o[4];  // o[dt]: q = l4*4 + r, d = dt*16 + l15
#pragma unroll
    for (int dt = 0; dt < 4; ++dt) o[dt] = f32x4{0.f, 0.f, 0.f, 0.f};
    float mrun = 0.f, lrun = 0.f;  // violation raises mrun if needed (T13)

    const unsigned long long* mr0 = mp + ((size_t)b * 2048 + q0 + l15) * 32;

    STAGE(0, 0)
    ulonglong2 mwv = *(const ulonglong2*)(mr0);   // words for tile 0 (halves 0,1)
    __syncthreads();

// one 64-token half. H = 0/1 selects LDS sub-tile; MW = mask word.
#define HALF(H, MW)                                                                  \
    {                                                                                \
        bf16x8 ka[4][2];                                                             \
        _Pragma("unroll") for (int tb = 0; tb < 4; ++tb)                             \
            _Pragma("unroll") for (int dc = 0; dc < 2; ++dc)                         \
                ka[tb][dc] = *(const bf16x8*)(Kc + (H) * 8192 +                      \
                                              (tb * 16 + l15) * 128 +                \
                                              16 * ((dc * 4 + l4) ^ swl));           \
        bf16x8 vb[4][2];                                                             \
        _Pragma("unroll") for (int dt = 0; dt < 4; ++dt)                             \
            _Pragma("unroll") for (int kb = 0; kb < 2; ++kb)                         \
                vb[dt][kb] = *(const bf16x8*)(Vc + (dt * 16 + l15) * 256 +           \
                                              (H) * 128 +                            \
                                              16 * ((kb * 4 + l4) ^ swl));           \
        const float nm = -mrun;                                                      \
        unsigned long long u64 = (MW) >> (l4 * 4);                                   \
        unsigned ulo = (unsigned)u64, uhi = (unsigned)(u64 >> 32);                   \
        f32x4 sv[4];                                                                 \
        _Pragma("unroll") for (int tb = 0; tb < 4; ++tb) {                           \
            unsigned us = (tb & 2) ? uhi : ulo;                                      \
            f32x4 i0;                                                                \
            _Pragma("unroll") for (int r = 0; r < 4; ++r)                            \
                i0[r] = (us & (1u << (((tb & 1) << 4) + r))) ? nm : -1e30f;          \
            sv[tb] = mfma16(ka[tb][1], qb[1], mfma16(ka[tb][0], qb[0], i0));         \
        }                                                                            \
        float pml;                                                                   \
        {                                                                            \
            f32x4 m0v;                                                               \
            _Pragma("unroll") for (int r = 0; r < 4; ++r)                            \
                m0v[r] = fmaxf(fmaxf(sv[0][r], sv[1][r]), fmaxf(sv[2][r], sv[3][r]));\
            pml = fmaxf(fmaxf(m0v[0], m0v[1]), fmaxf(m0v[2], m0v[3]));               \
        }                                                                            \
        if (__any(pml > 8.f)) {                                                      \
            float pm = fmaxf(pml, __shfl_xor(pml, 16, 64));                          \
            pm = fmaxf(pm, __shfl_xor(pm, 32, 64));                                  \
            float dm = fmaxf(pm, 0.f);                                               \
            float al = exp2f(-dm);                                                   \
            mrun += dm;                                                              \
            lrun *= al;                                                              \
            _Pragma("unroll") for (int r = 0; r < 4; ++r) {                          \
                float alr = __shfl(al, l4 * 4 + r, 64);                              \
                _Pragma("unroll") for (int dt = 0; dt < 4; ++dt) o[dt][r] *= alr;    \
            }                                                                        \
            _Pragma("unroll") for (int tb = 0; tb < 4; ++tb)                         \
                _Pragma("unroll") for (int r = 0; r < 4; ++r) sv[tb][r] -= dm;       \
        }                                                                            \
        _Pragma("unroll") for (int tb = 0; tb < 4; ++tb)                             \
            _Pragma("unroll") for (int r = 0; r < 4; ++r)                            \
                sv[tb][r] = exp2f(sv[tb][r]);                                        \
        {                                                                            \
            f32x4 t0 = (sv[0] + sv[1]) + (sv[2] + sv[3]);                            \
            lrun += (t0[0] + t0[1]) + (t0[2] + t0[3]);                               \
        }                                                                            \
        bf16x8 pa[2];                                                                \
        {                                                                            \
            uint4 t_;                                                                \
            asm("v_cvt_pk_bf16_f32 %0, %1, %2" : "=v"(t_.x) : "v"(sv[0][0]), "v"(sv[0][1])); \
            asm("v_cvt_pk_bf16_f32 %0, %1, %2" : "=v"(t_.y) : "v"(sv[0][2]), "v"(sv[0][3])); \
            asm("v_cvt_pk_bf16_f32 %0, %1, %2" : "=v"(t_.z) : "v"(sv[1][0]), "v"(sv[1][1])); \
            asm("v_cvt_pk_bf16_f32 %0, %1, %2" : "=v"(t_.w) : "v"(sv[1][2]), "v"(sv[1][3])); \
            pa[0] = *(bf16x8*)&t_;                                                   \
            asm("v_cvt_pk_bf16_f32 %0, %1, %2" : "=v"(t_.x) : "v"(sv[2][0]), "v"(sv[2][1])); \
            asm("v_cvt_pk_bf16_f32 %0, %1, %2" : "=v"(t_.y) : "v"(sv[2][2]), "v"(sv[2][3])); \
            asm("v_cvt_pk_bf16_f32 %0, %1, %2" : "=v"(t_.z) : "v"(sv[3][0]), "v"(sv[3][1])); \
            asm("v_cvt_pk_bf16_f32 %0, %1, %2" : "=v"(t_.w) : "v"(sv[3][2]), "v"(sv[3][3])); \
            pa[1] = *(bf16x8*)&t_;                                                   \
        }                                                                            \
        _Pragma("unroll") for (int dt = 0; dt < 4; ++dt)                             \
            o[dt] = mfma16(pa[1], vb[dt][1], mfma16(pa[0], vb[dt][0], o[dt]));       \
    }

    for (int kt = 0; kt < 16; ++kt) {
        const int cur = kt & 1;
        char* Kc = lds + cur * 16384;
        char* Vc = lds + 32768 + cur * 16384;
        if (kt < 15) STAGE(kt + 1, cur ^ 1)
        ulonglong2 mwn;
        mwn.x = 0; mwn.y = 0;
        if (kt < 15) mwn = *(const ulonglong2*)(mr0 + 2 * kt + 2);
        HALF(0, mwv.x)
        HALF(1, mwv.y)
        mwv = mwn;
        __syncthreads();  // drains next-tile staging + all LDS reads; swap buffers
    }
#undef HALF
#undef STAGE

    // epilogue: merge l4-group partial sums, normalize, store
    {
        float lt = lrun;
        lt += __shfl_xor(lt, 16, 64);
        lt += __shfl_xor(lt, 32, 64);
        float inv = 1.0f / lt;  // for q = q0 + l15
#pragma unroll
        for (int r = 0; r < 4; ++r) {
            float invr = __shfl(inv, l4 * 4 + r, 64);
            size_t base = ((size_t)b * 2048 + q0 + l4 * 4 + r) * 512 + h * 64;
#pragma unroll
            for (int dt = 0; dt < 4; ++dt)
                AO[base + dt * 16 + l15] = (short)f2bf(o[dt][r] * invr);
        }
    }
}

// ---------------- launcher ----------------
extern "C" void kernel_launch(void* const* d_in, const int* in_sizes, int n_in,
                              void* d_out, int out_size, void* d_ws, size_t ws_size,
                              hipStream_t stream) {
    const float* q  = (const float*)d_in[0];
    const float* k  = (const float*)d_in[1];
    const float* v  = (const float*)d_in[2];
    const int*   gm = (const int*)d_in[3];
    const float* Wq = (const float*)d_in[4];  const float* bq = (const float*)d_in[5];
    const float* Wk = (const float*)d_in[6];  const float* bk = (const float*)d_in[7];
    const float* Wv = (const float*)d_in[8];  const float* bv = (const float*)d_in[9];
    const float* Wo = (const float*)d_in[10]; const float* bo = (const float*)d_in[11];

    char* ws = (char*)d_ws;
    short* Xq  = (short*)(ws + 0);
    short* Xk  = (short*)(ws + 8388608);
    short* Xv  = (short*)(ws + 16777216);
    short* WqT = (short*)(ws + 25165824);
    short* WkT = (short*)(ws + 25690112);
    short* WvT = (short*)(ws + 26214400);
    short* WoT = (short*)(ws + 26738688);
    short* Qw  = (short*)(ws + 27262976);    // [b,h,tok,d] (pre-scaled)
    short* Kw  = (short*)(ws + 35651584);    // [b,h,tok,d]
    short* VTw = (short*)(ws + 44040192);    // [b,h,d,ptok] (token-permuted)
    short* AO  = (short*)(ws + 52428800);    // attn out [b,tok,h*64+d]
    unsigned long long* MP = (unsigned long long*)(ws + 60817408);

    prep_kernel<<<dim3(14848), 256, 0, stream>>>(q, k, v, gm, Wq, Wk, Wv, Wo,
                                                 Xq, Xk, Xv, WqT, WkT, WvT, WoT, MP);

    gemm_qkv_kernel<<<dim3(4, 128, 3), 256, 0, stream>>>(Xq, Xk, Xv, WqT, WkT, WvT,
                                                         bq, bk, bv, Qw, Kw, VTw);

    attn_kernel<<<dim3(512), 512, 0, stream>>>(Qw, Kw, VTw, MP, AO);

    gemm_kernel<<<dim3(4, 128), 256, 0, stream>>>(AO, WoT, bo, (void*)d_out, 3);
}